// Round 2
// baseline (237.769 us; speedup 1.0000x reference)
//
#include <hip/hip_runtime.h>

// Problem constants
#define BB   8
#define CC   128
#define CR   16      // reduced channels = 128/8
#define HH   128
#define WW   128
#define HWSZ 16384   // 128*128
#define K2   9

// ws layout (floats):
//   t      : [0, 2097152)                 (b, cr, h, w)
//   part   : [2097152, 2097152+16384)     512 blocks x 16 ch x {sum,sumsq}
//   stats  : next 256                     (b, cr) x {scale, shift}

__global__ __launch_bounds__(256) void k_conv1(const float* __restrict__ x,
                                               const float* __restrict__ w1,
                                               float* __restrict__ t,
                                               float* __restrict__ part) {
    const int tile = blockIdx.x;   // 0..63
    const int b    = blockIdx.y;   // 0..7
    const int tid  = threadIdx.x;
    const int pix  = tile * 256 + tid;

    __shared__ float w1s[CR * CC];   // 8 KB
    for (int i = tid; i < CR * CC; i += 256) w1s[i] = w1[i];
    __syncthreads();

    const float* xb = x + (size_t)b * CC * HWSZ + pix;
    float acc[CR];
#pragma unroll
    for (int o = 0; o < CR; ++o) acc[o] = 0.f;

    for (int cin = 0; cin < CC; ++cin) {
        float xv = xb[(size_t)cin * HWSZ];
#pragma unroll
        for (int o = 0; o < CR; ++o)
            acc[o] = fmaf(w1s[o * CC + cin], xv, acc[o]);
    }

    float* tb = t + (size_t)b * CR * HWSZ + pix;
#pragma unroll
    for (int o = 0; o < CR; ++o) tb[(size_t)o * HWSZ] = acc[o];

    // block-level sum / sumsq per reduced channel (deterministic, no atomics)
    __shared__ float red[4][CR][2];
    const int lane = tid & 63;
    const int wv   = tid >> 6;
#pragma unroll
    for (int o = 0; o < CR; ++o) {
        float s = acc[o];
        float q = s * s;
#pragma unroll
        for (int off = 32; off > 0; off >>= 1) {
            s += __shfl_down(s, off, 64);
            q += __shfl_down(q, off, 64);
        }
        if (lane == 0) { red[wv][o][0] = s; red[wv][o][1] = q; }
    }
    __syncthreads();
    if (tid < CR) {
        const int o = tid;
        float s = red[0][o][0] + red[1][o][0] + red[2][o][0] + red[3][o][0];
        float q = red[0][o][1] + red[1][o][1] + red[2][o][1] + red[3][o][1];
        const int blk = b * 64 + tile;
        part[blk * 32 + o * 2 + 0] = s;
        part[blk * 32 + o * 2 + 1] = q;
    }
}

__global__ void k_stats(const float* __restrict__ part,
                        const float* __restrict__ gamma,
                        const float* __restrict__ beta,
                        float* __restrict__ stats) {
    const int tid = threadIdx.x;           // 0..127
    if (tid >= BB * CR) return;
    const int b = tid / CR, o = tid % CR;
    float s = 0.f, q = 0.f;
    for (int tle = 0; tle < 64; ++tle) {
        const int blk = b * 64 + tle;
        s += part[blk * 32 + o * 2 + 0];
        q += part[blk * 32 + o * 2 + 1];
    }
    const float mean = s * (1.f / (float)HWSZ);
    const float var  = q * (1.f / (float)HWSZ) - mean * mean;
    const float rstd = rsqrtf(var + 1e-5f);
    const float sc   = gamma[o] * rstd;
    const float sh   = beta[o] - mean * sc;
    stats[tid * 2 + 0] = sc;
    stats[tid * 2 + 1] = sh;
}

// Fused weight-gen + dilated 3x3 involution apply.
// One thread owns ONE pixel x ALL 128 channels.
// Per-pixel invariants (tap offsets, masks, tn[16]) computed once, in VGPRs.
// grid = (64 ytiles, 8 batches); block = 256 (2 rows x 128 cols)
__global__ __launch_bounds__(256) void k_main(const float* __restrict__ x,
                                              const float* __restrict__ t,
                                              const float* __restrict__ stats,
                                              const float* __restrict__ w2,
                                              const float* __restrict__ b2,
                                              float* __restrict__ out) {
    const int tid  = threadIdx.x;
    const int xpos = tid & 127;
    const int y    = blockIdx.x * 2 + (tid >> 7);
    const int b    = blockIdx.y;
    const int pix  = y * WW + xpos;

    // per-pixel tap offsets (element idx, always in-bounds via wrap) + 0/1 masks
    int   off[K2];
    float msk[K2];
#pragma unroll
    for (int k = 0; k < K2; ++k) {
        const int dy = (k / 3) * 2 - 2;
        const int dx = (k % 3) * 2 - 2;
        const int yy = y + dy, xx = xpos + dx;
        const bool inb = ((unsigned)yy < (unsigned)HH) && ((unsigned)xx < (unsigned)WW);
        off[k] = (yy & (HH - 1)) * WW + (xx & (WW - 1));
        msk[k] = inb ? 1.f : 0.f;
    }

    // tn = relu(t * scale + shift), kept in VGPRs
    float tn[CR];
    {
        const float* tb = t + (size_t)b * CR * HWSZ + pix;
        const float* st = stats + b * CR * 2;
#pragma unroll
        for (int r = 0; r < CR; ++r) {
            float v = fmaf(tb[(size_t)r * HWSZ], st[r * 2], st[r * 2 + 1]);
            tn[r] = v > 0.f ? v : 0.f;
        }
    }

    const float* xc   = x   + (size_t)b * CC * HWSZ;   // wave-uniform, advances/ch
    float*       outb = out + (size_t)b * CC * HWSZ;   // wave-uniform, advances/ch

#pragma unroll 1
    for (int c = 0; c < CC; ++c) {
        // issue tap loads first so they overlap the weight-gen FMAs
        float pv[K2];
#pragma unroll
        for (int k = 0; k < K2; ++k) pv[k] = xc[off[k]];

        // w2/b2 rows: address depends only on loop counter -> wave-uniform -> s_load
        const float* w2r = w2 + (size_t)c * (K2 * CR);
        const float* b2r = b2 + (size_t)c * K2;

        float wv[K2];
#pragma unroll
        for (int k = 0; k < K2; ++k) wv[k] = b2r[k];

#pragma unroll
        for (int r = 0; r < CR; ++r) {
            const float tr = tn[r];
#pragma unroll
            for (int k = 0; k < K2; ++k)
                wv[k] = fmaf(w2r[k * CR + r], tr, wv[k]);
        }

        float acc = 0.f;
#pragma unroll
        for (int k = 0; k < K2; ++k)
            acc = fmaf(wv[k], pv[k] * msk[k], acc);

        outb[pix] = acc;
        xc   += HWSZ;
        outb += HWSZ;
    }
}

extern "C" void kernel_launch(void* const* d_in, const int* in_sizes, int n_in,
                              void* d_out, int out_size, void* d_ws, size_t ws_size,
                              hipStream_t stream) {
    const float* x     = (const float*)d_in[0];
    const float* w1    = (const float*)d_in[1];
    const float* gamma = (const float*)d_in[2];
    const float* beta  = (const float*)d_in[3];
    const float* w2    = (const float*)d_in[4];
    const float* b2    = (const float*)d_in[5];
    float* out = (float*)d_out;

    float* ws    = (float*)d_ws;
    float* t     = ws;                       // 2,097,152 floats
    float* part  = ws + 2097152;             // 16,384 floats
    float* stats = part + 16384;             // 256 floats

    dim3 gA(64, 8);
    k_conv1<<<gA, 256, 0, stream>>>(x, w1, t, part);

    k_stats<<<1, 128, 0, stream>>>(part, gamma, beta, stats);

    dim3 gC(64, 8);
    k_main<<<gC, 256, 0, stream>>>(x, t, stats, w2, b2, out);
}

// Round 3
// 138.077 us; speedup vs baseline: 1.7220x; 1.7220x over previous
//
#include <hip/hip_runtime.h>

// Problem constants
#define BB   8
#define CC   128
#define CR   16      // reduced channels = 128/8
#define HH   128
#define WW   128
#define HWSZ 16384   // 128*128
#define K2   9

// ws layout (floats):
//   t      : [0, 2097152)                 (b, cr, h, w)
//   part   : [2097152, 2097152+16384)     512 blocks x 16 ch x {sum,sumsq}
//   stats  : next 256                     (b, cr) x {scale, shift}

__global__ __launch_bounds__(256) void k_conv1(const float* __restrict__ x,
                                               const float* __restrict__ w1,
                                               float* __restrict__ t,
                                               float* __restrict__ part) {
    const int tile = blockIdx.x;   // 0..63
    const int b    = blockIdx.y;   // 0..7
    const int tid  = threadIdx.x;
    const int pix  = tile * 256 + tid;

    __shared__ float w1s[CR * CC];   // 8 KB
    for (int i = tid; i < CR * CC; i += 256) w1s[i] = w1[i];
    __syncthreads();

    const float* xb = x + (size_t)b * CC * HWSZ + pix;
    float acc[CR];
#pragma unroll
    for (int o = 0; o < CR; ++o) acc[o] = 0.f;

    for (int cin = 0; cin < CC; ++cin) {
        float xv = xb[(size_t)cin * HWSZ];
#pragma unroll
        for (int o = 0; o < CR; ++o)
            acc[o] = fmaf(w1s[o * CC + cin], xv, acc[o]);
    }

    float* tb = t + (size_t)b * CR * HWSZ + pix;
#pragma unroll
    for (int o = 0; o < CR; ++o) tb[(size_t)o * HWSZ] = acc[o];

    // block-level sum / sumsq per reduced channel (deterministic, no atomics)
    __shared__ float red[4][CR][2];
    const int lane = tid & 63;
    const int wv   = tid >> 6;
#pragma unroll
    for (int o = 0; o < CR; ++o) {
        float s = acc[o];
        float q = s * s;
#pragma unroll
        for (int off = 32; off > 0; off >>= 1) {
            s += __shfl_down(s, off, 64);
            q += __shfl_down(q, off, 64);
        }
        if (lane == 0) { red[wv][o][0] = s; red[wv][o][1] = q; }
    }
    __syncthreads();
    if (tid < CR) {
        const int o = tid;
        float s = red[0][o][0] + red[1][o][0] + red[2][o][0] + red[3][o][0];
        float q = red[0][o][1] + red[1][o][1] + red[2][o][1] + red[3][o][1];
        const int blk = b * 64 + tile;
        part[blk * 32 + o * 2 + 0] = s;
        part[blk * 32 + o * 2 + 1] = q;
    }
}

__global__ void k_stats(const float* __restrict__ part,
                        const float* __restrict__ gamma,
                        const float* __restrict__ beta,
                        float* __restrict__ stats) {
    const int tid = threadIdx.x;           // 0..127
    if (tid >= BB * CR) return;
    const int b = tid / CR, o = tid % CR;
    float s = 0.f, q = 0.f;
    for (int tle = 0; tle < 64; ++tle) {
        const int blk = b * 64 + tle;
        s += part[blk * 32 + o * 2 + 0];
        q += part[blk * 32 + o * 2 + 1];
    }
    const float mean = s * (1.f / (float)HWSZ);
    const float var  = q * (1.f / (float)HWSZ) - mean * mean;
    const float rstd = rsqrtf(var + 1e-5f);
    const float sc   = gamma[o] * rstd;
    const float sh   = beta[o] - mean * sc;
    stats[tid * 2 + 0] = sc;
    stats[tid * 2 + 1] = sh;
}

// Fused weight-gen + dilated 3x3 involution apply.
// One thread: 1 pixel x 16 channels (channel group = blockIdx.z).
// Per-pixel invariants (tap offsets, masks, tn[16]) hoisted into VGPRs.
// grid = (64 ytiles, 8 batches, 8 ch-groups); block = 256 (2 rows x 128 cols)
__global__ __launch_bounds__(256) void k_main(const float* __restrict__ x,
                                              const float* __restrict__ t,
                                              const float* __restrict__ stats,
                                              const float* __restrict__ w2,
                                              const float* __restrict__ b2,
                                              float* __restrict__ out) {
    const int tid  = threadIdx.x;
    const int xpos = tid & 127;
    const int y    = blockIdx.x * 2 + (tid >> 7);
    const int b    = blockIdx.y;
    const int ch0  = blockIdx.z * 16;
    const int pix  = y * WW + xpos;

    // per-pixel tap offsets (element idx, wrapped in-bounds) + 0/1 masks
    int   off[K2];
    float msk[K2];
#pragma unroll
    for (int k = 0; k < K2; ++k) {
        const int dy = (k / 3) * 2 - 2;
        const int dx = (k % 3) * 2 - 2;
        const int yy = y + dy, xx = xpos + dx;
        const bool inb = ((unsigned)yy < (unsigned)HH) && ((unsigned)xx < (unsigned)WW);
        off[k] = (yy & (HH - 1)) * WW + (xx & (WW - 1));
        msk[k] = inb ? 1.f : 0.f;
    }

    // tn = relu(t * scale + shift), kept in VGPRs
    float tn[CR];
    {
        const float* tb = t + (size_t)b * CR * HWSZ + pix;
        const float* st = stats + b * CR * 2;
#pragma unroll
        for (int r = 0; r < CR; ++r) {
            float v = fmaf(tb[(size_t)r * HWSZ], st[r * 2], st[r * 2 + 1]);
            tn[r] = v > 0.f ? v : 0.f;
        }
    }

    const float* xc   = x   + ((size_t)b * CC + ch0) * HWSZ;   // advances per ch
    float*       outb = out + ((size_t)b * CC + ch0) * HWSZ;

#pragma unroll 1
    for (int cc = 0; cc < 16; ++cc) {
        // issue tap loads first so they overlap the weight-gen FMAs
        float pv[K2];
#pragma unroll
        for (int k = 0; k < K2; ++k) pv[k] = xc[off[k]];

        // w2/b2 rows: address depends only on blockIdx.z + loop counter
        //   -> wave-uniform -> scalar loads
        const int c = ch0 + cc;
        const float* w2r = w2 + (size_t)c * (K2 * CR);
        const float* b2r = b2 + (size_t)c * K2;

        float wv[K2];
#pragma unroll
        for (int k = 0; k < K2; ++k) wv[k] = b2r[k];

#pragma unroll
        for (int r = 0; r < CR; ++r) {
            const float tr = tn[r];
#pragma unroll
            for (int k = 0; k < K2; ++k)
                wv[k] = fmaf(w2r[k * CR + r], tr, wv[k]);
        }

        float acc = 0.f;
#pragma unroll
        for (int k = 0; k < K2; ++k)
            acc = fmaf(wv[k], pv[k] * msk[k], acc);

        outb[pix] = acc;
        xc   += HWSZ;
        outb += HWSZ;
    }
}

extern "C" void kernel_launch(void* const* d_in, const int* in_sizes, int n_in,
                              void* d_out, int out_size, void* d_ws, size_t ws_size,
                              hipStream_t stream) {
    const float* x     = (const float*)d_in[0];
    const float* w1    = (const float*)d_in[1];
    const float* gamma = (const float*)d_in[2];
    const float* beta  = (const float*)d_in[3];
    const float* w2    = (const float*)d_in[4];
    const float* b2    = (const float*)d_in[5];
    float* out = (float*)d_out;

    float* ws    = (float*)d_ws;
    float* t     = ws;                       // 2,097,152 floats
    float* part  = ws + 2097152;             // 16,384 floats
    float* stats = part + 16384;             // 256 floats

    dim3 gA(64, 8);
    k_conv1<<<gA, 256, 0, stream>>>(x, w1, t, part);

    k_stats<<<1, 128, 0, stream>>>(part, gamma, beta, stats);

    dim3 gC(64, 8, 8);
    k_main<<<gC, 256, 0, stream>>>(x, t, stats, w2, b2, out);
}

// Round 4
// 117.263 us; speedup vs baseline: 2.0277x; 1.1775x over previous
//
#include <hip/hip_runtime.h>

// Problem constants
#define BB   8
#define CC   128
#define CR   16      // reduced channels = 128/8
#define HH   128
#define WW   128
#define HWSZ 16384   // 128*128
#define K2   9
#define NFRAG 72     // 8 ctiles * 9 taps

typedef _Float16 f16x8 __attribute__((ext_vector_type(8)));
typedef float    f32x4 __attribute__((ext_vector_type(4)));

// ws layout (float slots):
//   t     : [0, 2097152)             (b, cr, h, w) fp32
//   part  : [2097152, +16384)
//   stats : [2113536, +256)          (b,cr) x {scale,shift}
//   b2f   : [2113792, +1152)         C-in fragments (ct,k,row) fp32
//   afrag : [2114944, +18432)        A fragments, f16x8 per lane (16B aligned)
#define WS_T     0
#define WS_PART  2097152
#define WS_STATS 2113536
#define WS_B2F   2113792
#define WS_AFRAG 2114944

__global__ __launch_bounds__(256) void k_conv1(const float* __restrict__ x,
                                               const float* __restrict__ w1,
                                               float* __restrict__ t,
                                               float* __restrict__ part) {
    const int tile = blockIdx.x;   // 0..63
    const int b    = blockIdx.y;   // 0..7
    const int tid  = threadIdx.x;
    const int pix  = tile * 256 + tid;

    __shared__ float w1s[CR * CC];   // 8 KB
    for (int i = tid; i < CR * CC; i += 256) w1s[i] = w1[i];
    __syncthreads();

    const float* xb = x + (size_t)b * CC * HWSZ + pix;
    float acc[CR];
#pragma unroll
    for (int o = 0; o < CR; ++o) acc[o] = 0.f;

    for (int cin = 0; cin < CC; ++cin) {
        float xv = xb[(size_t)cin * HWSZ];
#pragma unroll
        for (int o = 0; o < CR; ++o)
            acc[o] = fmaf(w1s[o * CC + cin], xv, acc[o]);
    }

    float* tb = t + (size_t)b * CR * HWSZ + pix;
#pragma unroll
    for (int o = 0; o < CR; ++o) tb[(size_t)o * HWSZ] = acc[o];

    __shared__ float red[4][CR][2];
    const int lane = tid & 63;
    const int wv   = tid >> 6;
#pragma unroll
    for (int o = 0; o < CR; ++o) {
        float s = acc[o];
        float q = s * s;
#pragma unroll
        for (int off = 32; off > 0; off >>= 1) {
            s += __shfl_down(s, off, 64);
            q += __shfl_down(q, off, 64);
        }
        if (lane == 0) { red[wv][o][0] = s; red[wv][o][1] = q; }
    }
    __syncthreads();
    if (tid < CR) {
        const int o = tid;
        float s = red[0][o][0] + red[1][o][0] + red[2][o][0] + red[3][o][0];
        float q = red[0][o][1] + red[1][o][1] + red[2][o][1] + red[3][o][1];
        const int blk = b * 64 + tile;
        part[blk * 32 + o * 2 + 0] = s;
        part[blk * 32 + o * 2 + 1] = q;
    }
}

__global__ void k_stats(const float* __restrict__ part,
                        const float* __restrict__ gamma,
                        const float* __restrict__ beta,
                        float* __restrict__ stats) {
    const int tid = threadIdx.x;           // 0..127
    if (tid >= BB * CR) return;
    const int b = tid / CR, o = tid % CR;
    float s = 0.f, q = 0.f;
    for (int tle = 0; tle < 64; ++tle) {
        const int blk = b * 64 + tle;
        s += part[blk * 32 + o * 2 + 0];
        q += part[blk * 32 + o * 2 + 1];
    }
    const float mean = s * (1.f / (float)HWSZ);
    const float var  = q * (1.f / (float)HWSZ) - mean * mean;
    const float rstd = rsqrtf(var + 1e-5f);
    const float sc   = gamma[o] * rstd;
    const float sh   = beta[o] - mean * sc;
    stats[tid * 2 + 0] = sc;
    stats[tid * 2 + 1] = sh;
}

// Pre-swizzle w2 into MFMA A-fragments (f16) and b2 into C-in fragments.
// A-frag (16x16x32_f16): lane holds A[row=lane&15][kk=8*(lane>>4)+i], i=0..7.
// frag index = ct*9+k; A[row][kk] = w2[((ct*16+row)*9+k)*16 + kk] (kk<16 else 0)
__global__ __launch_bounds__(256) void k_prep(const float* __restrict__ w2,
                                              const float* __restrict__ b2,
                                              float* __restrict__ ws) {
    const int id = blockIdx.x * 256 + threadIdx.x;
    if (id < NFRAG * 64) {
        const int lane = id & 63;
        const int frag = id >> 6;           // ct*9 + k
        const int ct = frag / 9, k = frag - ct * 9;
        const int row = lane & 15, lg = lane >> 4;
        f16x8 v;
#pragma unroll
        for (int i = 0; i < 8; ++i) {
            const int kk = lg * 8 + i;
            float w = (kk < CR) ? w2[(size_t)((ct * 16 + row) * K2 + k) * CR + kk] : 0.f;
            v[i] = (_Float16)w;
        }
        f16x8* dst = (f16x8*)(ws + WS_AFRAG);
        dst[frag * 64 + lane] = v;
    }
    if (id < NFRAG * 16) {
        const int frag = id >> 4;           // ct*9 + k
        const int row  = id & 15;
        const int ct = frag / 9, k = frag - ct * 9;
        ws[WS_B2F + frag * 16 + row] = b2[(ct * 16 + row) * K2 + k];
    }
}

// Fused MFMA weight-gen + dilated 3x3 involution apply.
// Wave owns 16 consecutive pixels (one row) x all 128 channels.
// Per (ctile,k): wgt = mfma(afrag, tnfrag, b2frag); acc[reg] += wgt*x_tap.
// grid = (2 strips * 128 rows, 8 batches); block = 256 (4 waves).
__global__ __launch_bounds__(256) void k_main(const float* __restrict__ x,
                                              const float* __restrict__ ws,
                                              float* __restrict__ out) {
    const int tid  = threadIdx.x;
    const int wv   = tid >> 6;
    const int lane = tid & 63;
    const int lg   = lane >> 4;           // 0..3
    const int ln   = lane & 15;
    const int y    = blockIdx.x >> 1;
    const int col  = (blockIdx.x & 1) * 64 + wv * 16 + ln;
    const int b    = blockIdx.y;

    // B-fragment: tn[kk][pix], kk = 8*lg + i (valid kk<16 -> lanes lg<2)
    f16x8 tnf = {};
    if (lg < 2) {
        const float* tb = ws + WS_T + (size_t)b * CR * HWSZ + y * WW + col;
        const float* st = ws + WS_STATS + b * CR * 2;
#pragma unroll
        for (int i = 0; i < 8; ++i) {
            const int r = lg * 8 + i;
            float v = fmaf(tb[(size_t)r * HWSZ], st[r * 2], st[r * 2 + 1]);
            v = v > 0.f ? v : 0.f;
            tnf[i] = (_Float16)v;
        }
    }

    // per-lane tap offsets (wrapped) + 0/1 masks for this pixel
    int   off[K2];
    float msk[K2];
#pragma unroll
    for (int k = 0; k < K2; ++k) {
        const int dy = (k / 3) * 2 - 2;
        const int dx = (k % 3) * 2 - 2;
        const int yy = y + dy, xx = col + dx;
        const bool inb = ((unsigned)yy < (unsigned)HH) && ((unsigned)xx < (unsigned)WW);
        off[k] = (yy & (HH - 1)) * WW + (xx & (WW - 1));
        msk[k] = inb ? 1.f : 0.f;
    }

    const f16x8* afrag = (const f16x8*)(ws + WS_AFRAG);
    const float* b2f   = ws + WS_B2F;
    const float* xb    = x   + (size_t)b * CC * HWSZ;
    float*       ob    = out + (size_t)b * CC * HWSZ;
    const int crow = lg * 4;              // channel row group within ctile

#pragma unroll 1
    for (int ct = 0; ct < 8; ++ct) {
        const int c0 = ct * 16;
        f32x4 acc = {0.f, 0.f, 0.f, 0.f};
#pragma unroll
        for (int k = 0; k < K2; ++k) {
            const int frag = ct * 9 + k;
            const f16x8 af = afrag[frag * 64 + lane];
            const f32x4 b2v = *(const f32x4*)(b2f + frag * 16 + crow);
            const f32x4 wgt = __builtin_amdgcn_mfma_f32_16x16x32_f16(af, tnf, b2v, 0, 0, 0);
            const float* xc = xb + (size_t)(c0 + crow) * HWSZ + off[k];
            const float m = msk[k];
#pragma unroll
            for (int reg = 0; reg < 4; ++reg) {
                const float xv = xc[(size_t)reg * HWSZ];
                acc[reg] = fmaf(wgt[reg], xv * m, acc[reg]);
            }
        }
        float* oc = ob + (size_t)(c0 + crow) * HWSZ + y * WW + col;
#pragma unroll
        for (int reg = 0; reg < 4; ++reg)
            oc[(size_t)reg * HWSZ] = acc[reg];
    }
}

extern "C" void kernel_launch(void* const* d_in, const int* in_sizes, int n_in,
                              void* d_out, int out_size, void* d_ws, size_t ws_size,
                              hipStream_t stream) {
    const float* x     = (const float*)d_in[0];
    const float* w1    = (const float*)d_in[1];
    const float* gamma = (const float*)d_in[2];
    const float* beta  = (const float*)d_in[3];
    const float* w2    = (const float*)d_in[4];
    const float* b2    = (const float*)d_in[5];
    float* out = (float*)d_out;

    float* ws = (float*)d_ws;

    dim3 gA(64, 8);
    k_conv1<<<gA, 256, 0, stream>>>(x, w1, ws + WS_T, ws + WS_PART);

    k_stats<<<1, 128, 0, stream>>>(ws + WS_PART, gamma, beta, ws + WS_STATS);

    k_prep<<<18, 256, 0, stream>>>(w2, b2, ws);

    dim3 gC(256, 8);
    k_main<<<gC, 256, 0, stream>>>(x, ws, out);
}

// Round 5
// 92.294 us; speedup vs baseline: 2.5762x; 1.2705x over previous
//
#include <hip/hip_runtime.h>

// Problem constants
#define BB   8
#define CC   128
#define CR   16      // reduced channels = 128/8
#define HH   128
#define WW   128
#define HWSZ 16384   // 128*128
#define K2   9
#define NFRAG 72     // 8 ctiles * 9 taps
#define CTPB 2       // ctiles per block in k_main (z = 4 channel groups)

typedef _Float16 f16x8 __attribute__((ext_vector_type(8)));
typedef float    f32x4 __attribute__((ext_vector_type(4)));

// ws layout (float slots):
//   t     : [0, 2097152)             (b, cr, h, w) fp32
//   part  : [2097152, +16384)
//   stats : [2113536, +256)          (b,cr) x {scale,shift}
//   b2f   : [2113792, +1152)         C-in fragments (frag,row) fp32
//   afrag : [2114944, +18432)        A fragments, f16x8 per lane (16B aligned)
#define WS_T     0
#define WS_PART  2097152
#define WS_STATS 2113536
#define WS_B2F   2113792
#define WS_AFRAG 2114944

__global__ __launch_bounds__(256) void k_conv1(const float* __restrict__ x,
                                               const float* __restrict__ w1,
                                               float* __restrict__ t,
                                               float* __restrict__ part) {
    const int tile = blockIdx.x;   // 0..63
    const int b    = blockIdx.y;   // 0..7
    const int tid  = threadIdx.x;
    const int pix  = tile * 256 + tid;

    __shared__ float w1s[CR * CC];   // 8 KB
    for (int i = tid; i < CR * CC; i += 256) w1s[i] = w1[i];
    __syncthreads();

    const float* xb = x + (size_t)b * CC * HWSZ + pix;
    float acc[CR];
#pragma unroll
    for (int o = 0; o < CR; ++o) acc[o] = 0.f;

    for (int cin = 0; cin < CC; ++cin) {
        float xv = xb[(size_t)cin * HWSZ];
#pragma unroll
        for (int o = 0; o < CR; ++o)
            acc[o] = fmaf(w1s[o * CC + cin], xv, acc[o]);
    }

    float* tb = t + (size_t)b * CR * HWSZ + pix;
#pragma unroll
    for (int o = 0; o < CR; ++o) tb[(size_t)o * HWSZ] = acc[o];

    __shared__ float red[4][CR][2];
    const int lane = tid & 63;
    const int wv   = tid >> 6;
#pragma unroll
    for (int o = 0; o < CR; ++o) {
        float s = acc[o];
        float q = s * s;
#pragma unroll
        for (int off = 32; off > 0; off >>= 1) {
            s += __shfl_down(s, off, 64);
            q += __shfl_down(q, off, 64);
        }
        if (lane == 0) { red[wv][o][0] = s; red[wv][o][1] = q; }
    }
    __syncthreads();
    if (tid < CR) {
        const int o = tid;
        float s = red[0][o][0] + red[1][o][0] + red[2][o][0] + red[3][o][0];
        float q = red[0][o][1] + red[1][o][1] + red[2][o][1] + red[3][o][1];
        const int blk = b * 64 + tile;
        part[blk * 32 + o * 2 + 0] = s;
        part[blk * 32 + o * 2 + 1] = q;
    }
}

// grid = 128 blocks (b*16+o), block = 64 threads; wave-reduce over 64 tiles
__global__ void k_stats(const float* __restrict__ part,
                        const float* __restrict__ gamma,
                        const float* __restrict__ beta,
                        float* __restrict__ stats) {
    const int b   = blockIdx.x >> 4;
    const int o   = blockIdx.x & 15;
    const int tle = threadIdx.x;            // 0..63
    float s = part[(b * 64 + tle) * 32 + o * 2 + 0];
    float q = part[(b * 64 + tle) * 32 + o * 2 + 1];
#pragma unroll
    for (int off = 32; off > 0; off >>= 1) {
        s += __shfl_down(s, off, 64);
        q += __shfl_down(q, off, 64);
    }
    if (tle == 0) {
        const float mean = s * (1.f / (float)HWSZ);
        const float var  = q * (1.f / (float)HWSZ) - mean * mean;
        const float rstd = rsqrtf(var + 1e-5f);
        const float sc   = gamma[o] * rstd;
        const float sh   = beta[o] - mean * sc;
        stats[(b * CR + o) * 2 + 0] = sc;
        stats[(b * CR + o) * 2 + 1] = sh;
    }
}

// Pre-swizzle w2 into MFMA A-fragments (f16) and b2 into C-in fragments.
// A-frag (16x16x32_f16): lane holds A[row=lane&15][kk=8*(lane>>4)+i], i=0..7.
__global__ __launch_bounds__(256) void k_prep(const float* __restrict__ w2,
                                              const float* __restrict__ b2,
                                              float* __restrict__ ws) {
    const int id = blockIdx.x * 256 + threadIdx.x;
    if (id < NFRAG * 64) {
        const int lane = id & 63;
        const int frag = id >> 6;           // ct*9 + k
        const int ct = frag / 9, k = frag - ct * 9;
        const int row = lane & 15, lg = lane >> 4;
        f16x8 v;
#pragma unroll
        for (int i = 0; i < 8; ++i) {
            const int kk = lg * 8 + i;
            float w = (kk < CR) ? w2[(size_t)((ct * 16 + row) * K2 + k) * CR + kk] : 0.f;
            v[i] = (_Float16)w;
        }
        f16x8* dst = (f16x8*)(ws + WS_AFRAG);
        dst[frag * 64 + lane] = v;
    }
    if (id < NFRAG * 16) {
        const int frag = id >> 4;           // ct*9 + k
        const int row  = id & 15;
        const int ct = frag / 9, k = frag - ct * 9;
        ws[WS_B2F + frag * 16 + row] = b2[(ct * 16 + row) * K2 + k];
    }
}

// Fused MFMA weight-gen + dilated 3x3 involution apply.
// Block: 4 waves x 16 px (64 px of one row) x 32 channels (2 ctiles).
// A/b2 fragments staged in LDS once per block -> MFMA feeds from ds_read.
// grid = (128 y * 2 xhalf, 8 batches, 4 chgroups); block = 256.
__global__ __launch_bounds__(256) void k_main(const float* __restrict__ x,
                                              const float* __restrict__ ws,
                                              float* __restrict__ out) {
    __shared__ float4 lds4[1224];   // [0,1152) af (18 frags x 64 lanes x 16B), [1152,1224) b2

    const int tid  = threadIdx.x;
    const int wv   = tid >> 6;
    const int lane = tid & 63;
    const int lg   = lane >> 4;           // 0..3
    const int ln   = lane & 15;
    const int y    = blockIdx.x >> 1;
    const int col  = (blockIdx.x & 1) * 64 + wv * 16 + ln;
    const int b    = blockIdx.y;
    const int z    = blockIdx.z;          // channel group: ctiles {2z, 2z+1}
    const int frag0 = z * (CTPB * K2);    // 18 frags per group

    // ---- cooperative stage of A-frags + b2-frags into LDS ----
    {
        const float4* asrc = (const float4*)(ws + WS_AFRAG) + (size_t)frag0 * 64;
        for (int i = tid; i < CTPB * K2 * 64; i += 256) lds4[i] = asrc[i];
        const float4* bsrc = (const float4*)(ws + WS_B2F) + (size_t)frag0 * 4;
        if (tid < CTPB * K2 * 4) lds4[1152 + tid] = bsrc[tid];
    }

    // B-fragment: tn[kk][pix], kk = 8*lg + i (valid kk<16 -> lanes lg<2)
    f16x8 tnf = {};
    if (lg < 2) {
        const float* tb = ws + WS_T + (size_t)b * CR * HWSZ + y * WW + col;
        const float* st = ws + WS_STATS + b * CR * 2;
#pragma unroll
        for (int i = 0; i < 8; ++i) {
            const int r = lg * 8 + i;
            float v = fmaf(tb[(size_t)r * HWSZ], st[r * 2], st[r * 2 + 1]);
            v = v > 0.f ? v : 0.f;
            tnf[i] = (_Float16)v;
        }
    }

    // per-lane tap offsets (wrapped in-bounds) + 0/1 masks
    int   off[K2];
    float msk[K2];
#pragma unroll
    for (int k = 0; k < K2; ++k) {
        const int dy = (k / 3) * 2 - 2;
        const int dx = (k % 3) * 2 - 2;
        const int yy = y + dy, xx = col + dx;
        const bool inb = ((unsigned)yy < (unsigned)HH) && ((unsigned)xx < (unsigned)WW);
        off[k] = (yy & (HH - 1)) * WW + (xx & (WW - 1));
        msk[k] = inb ? 1.f : 0.f;
    }

    __syncthreads();

    const f16x8* afl = (const f16x8*)lds4;             // 18 x 64
    const float* b2l = (const float*)(lds4 + 1152);    // 18 x 16
    const float* xb  = x   + (size_t)b * CC * HWSZ;
    float*       ob  = out + (size_t)b * CC * HWSZ;
    const int crow = lg * 4;              // channel row group within ctile

#pragma unroll
    for (int cti = 0; cti < CTPB; ++cti) {
        const int c0 = (z * CTPB + cti) * 16;
        f32x4 acc = {0.f, 0.f, 0.f, 0.f};
#pragma unroll
        for (int k = 0; k < K2; ++k) {
            const int fl = cti * K2 + k;
            const f16x8 af  = afl[fl * 64 + lane];
            const f32x4 b2v = *(const f32x4*)(b2l + fl * 16 + crow);
            const f32x4 wgt = __builtin_amdgcn_mfma_f32_16x16x32_f16(af, tnf, b2v, 0, 0, 0);
            const float* xc = xb + (size_t)(c0 + crow) * HWSZ + off[k];
            const float m = msk[k];
#pragma unroll
            for (int reg = 0; reg < 4; ++reg) {
                const float xv = xc[(size_t)reg * HWSZ];
                acc[reg] = fmaf(wgt[reg], xv * m, acc[reg]);
            }
        }
        float* oc = ob + (size_t)(c0 + crow) * HWSZ + y * WW + col;
#pragma unroll
        for (int reg = 0; reg < 4; ++reg)
            oc[(size_t)reg * HWSZ] = acc[reg];
    }
}

extern "C" void kernel_launch(void* const* d_in, const int* in_sizes, int n_in,
                              void* d_out, int out_size, void* d_ws, size_t ws_size,
                              hipStream_t stream) {
    const float* x     = (const float*)d_in[0];
    const float* w1    = (const float*)d_in[1];
    const float* gamma = (const float*)d_in[2];
    const float* beta  = (const float*)d_in[3];
    const float* w2    = (const float*)d_in[4];
    const float* b2    = (const float*)d_in[5];
    float* out = (float*)d_out;

    float* ws = (float*)d_ws;

    dim3 gA(64, 8);
    k_conv1<<<gA, 256, 0, stream>>>(x, w1, ws + WS_T, ws + WS_PART);

    k_stats<<<128, 64, 0, stream>>>(ws + WS_PART, gamma, beta, ws + WS_STATS);

    k_prep<<<18, 256, 0, stream>>>(w2, b2, ws);

    dim3 gC(256, 8, 4);
    k_main<<<gC, 256, 0, stream>>>(x, ws, out);
}